// Round 6
// baseline (74.655 us; speedup 1.0000x reference)
//
#include <hip/hip_runtime.h>
#include <hip/hip_bf16.h>

typedef short bf16x8 __attribute__((ext_vector_type(8)));
typedef float f32x4  __attribute__((ext_vector_type(4)));

#define NB 64
#define NN 512
#define DD 128

// RNE float -> bf16 (finite inputs)
__device__ __forceinline__ unsigned short f2bf(float f) {
    unsigned int u = __float_as_uint(f);
    unsigned int r = (u + 0x7FFFu + ((u >> 16) & 1u)) >> 16;
    return (unsigned short)r;
}

// Load 8 consecutive f32 and RNE-cast to a bf16x8 MFMA fragment.
__device__ __forceinline__ bf16x8 load_frag8(const float* __restrict__ p) {
    const f32x4 a = *reinterpret_cast<const f32x4*>(p);
    const f32x4 b = *reinterpret_cast<const f32x4*>(p + 4);
    bf16x8 r;
    r[0] = (short)f2bf(a[0]); r[1] = (short)f2bf(a[1]);
    r[2] = (short)f2bf(a[2]); r[3] = (short)f2bf(a[3]);
    r[4] = (short)f2bf(b[0]); r[5] = (short)f2bf(b[1]);
    r[6] = (short)f2bf(b[2]); r[7] = (short)f2bf(b[3]);
    return r;
}

// Single fused kernel. Per (batch, 128x64 tile); 4 waves, each owns 64x32.
// cos(i,j) = <f_i,f_j> * rs_i * rs_j  — MFMA on raw bf16-cast features,
// reciprocal norms applied in the epilogue. No norm kernel, no workspace.
__global__ __launch_bounds__(256, 4) void ASG_fused_kernel(
    const float* __restrict__ fea, const float* __restrict__ coord,
    float* __restrict__ out)
{
    const int id  = blockIdx.x;        // 0..2047
    const int xcd = id & 7;            // dispatch round-robins blocks % 8 XCDs
    const int q   = id >> 3;           // 0..255
    const int b   = xcd + 8 * (q >> 5);
    const int t   = q & 31;
    const int bi  = t >> 3;            // 128-row stripe 0..3
    const int bj  = t & 7;             // 64-col stripe 0..7

    const int tid = threadIdx.x;
    const int wid = tid >> 6, lane = tid & 63;
    const int wr  = wid >> 1, wc = wid & 1;
    const int row0 = bi * 128 + wr * 64;
    const int col0 = bj * 64  + wc * 32;
    const int lo = lane & 15, hi = lane >> 4;

    __shared__ float  rsA[128];
    __shared__ float  rsB[64];
    __shared__ float2 crow[128];
    __shared__ float2 ccol[64];
    __shared__ float  xpose[4][16 * 36];   // per-wave transpose buf (pad 36)

    const float* feab = fea + (size_t)b * NN * DD;

    // Prologue: threads 0..191 compute one row's reciprocal norm each
    // (full 128-float row = 32 x f32x4); threads 192..255 load the coords.
    if (tid < 192) {
        const int row = (tid < 128) ? (bi * 128 + tid) : (bj * 64 + tid - 128);
        const f32x4* rp = reinterpret_cast<const f32x4*>(feab + (size_t)row * DD);
        f32x4 s4 = (f32x4){0.f, 0.f, 0.f, 0.f};
#pragma unroll
        for (int k = 0; k < 32; ++k) {    // 32 * 4 = 128 elements (R5 fix)
            const f32x4 x = rp[k];
            s4 += x * x;
        }
        const float s = (s4[0] + s4[1]) + (s4[2] + s4[3]);
        const float rs = 1.0f / fmaxf(sqrtf(s), 1e-8f);
        if (tid < 128) rsA[tid] = rs;
        else           rsB[tid - 128] = rs;
    } else {
        const int u = tid - 192;       // 0..63
        const float2* cb = reinterpret_cast<const float2*>(coord) + (size_t)b * NN;
        crow[u]      = cb[bi * 128 + u];
        crow[u + 64] = cb[bi * 128 + u + 64];
        ccol[u]      = cb[bj * 64 + u];
    }
    __syncthreads();

    const int lk = hi * 8;             // k start (f32 elements)

    // B fragments: col = col0 + n*16 + lo
    bf16x8 bfrag[2][4];
#pragma unroll
    for (int n = 0; n < 2; ++n) {
        const float* p = feab + (size_t)(col0 + n * 16 + lo) * DD + lk;
#pragma unroll
        for (int kk = 0; kk < 4; ++kk)
            bfrag[n][kk] = load_frag8(p + kk * 32);
    }

    float* outA = out + (size_t)b * NN * NN;
    float* outS = out + (size_t)NB * NN * NN + (size_t)b * NN * NN;
    float* xp = xpose[wid];

    // this lane's 4 output columns (after transpose): jbase..jbase+3
    const int c4 = (lane & 7) * 4;
    const int jbase = col0 + c4;
    float2 cj[4];
#pragma unroll
    for (int q2 = 0; q2 < 4; ++q2) cj[q2] = ccol[wc * 32 + c4 + q2];
    const f32x4 rsb4 = *reinterpret_cast<const f32x4*>(&rsB[wc * 32 + c4]);

#pragma unroll
    for (int m = 0; m < 4; ++m) {
        // A fragments for this 16-row group
        const float* p = feab + (size_t)(row0 + m * 16 + lo) * DD + lk;
        bf16x8 afrag[4];
#pragma unroll
        for (int kk = 0; kk < 4; ++kk)
            afrag[kk] = load_frag8(p + kk * 32);

        f32x4 acc[2];
#pragma unroll
        for (int n = 0; n < 2; ++n) acc[n] = (f32x4){0.f, 0.f, 0.f, 0.f};
#pragma unroll
        for (int n = 0; n < 2; ++n)
#pragma unroll
            for (int kk = 0; kk < 4; ++kk)
                acc[n] = __builtin_amdgcn_mfma_f32_16x16x32_bf16(
                    afrag[kk], bfrag[n][kk], acc[n], 0, 0, 0);

        // scatter into LDS: [local_row][local_col], stride 36
#pragma unroll
        for (int n = 0; n < 2; ++n)
#pragma unroll
            for (int r = 0; r < 4; ++r)
                xp[(hi * 4 + r) * 36 + n * 16 + lo] = acc[n][r];

        // read back transposed: 8 rows x 32 cols per pass, dwordx4/lane
#pragma unroll
        for (int p2 = 0; p2 < 2; ++p2) {
            const int rr = p2 * 8 + (lane >> 3);       // local row 0..15
            const f32x4 cv = *reinterpret_cast<const f32x4*>(&xp[rr * 36 + c4]);
            const int i = row0 + m * 16 + rr;
            const float rsi = rsA[wr * 64 + m * 16 + rr];
            const float2 ci = crow[wr * 64 + m * 16 + rr];
            f32x4 av, sv;
#pragma unroll
            for (int q2 = 0; q2 < 4; ++q2) {
                const int j = jbase + q2;
                // bit-exact match to numpy: mul, mul, add, sqrt (no FMA)
                const float dx = ci.x - cj[q2].x;
                const float dy = ci.y - cj[q2].y;
                const float d2 = __fadd_rn(__fmul_rn(dx, dx), __fmul_rn(dy, dy));
                const float dist = __fsqrt_rn(d2);
                const bool diag = (i == j);
                av[q2] = diag ? 0.0f
                              : cv[q2] * rsi * rsb4[q2] * __expf(-dist);
                sv[q2] = (!diag && dist < 1.0f) ? 1.0f : 0.0f;
            }
            const size_t off = (size_t)i * NN + jbase;
            __builtin_nontemporal_store(av, reinterpret_cast<f32x4*>(outA + off));
            __builtin_nontemporal_store(sv, reinterpret_cast<f32x4*>(outS + off));
        }
    }
}

extern "C" void kernel_launch(void* const* d_in, const int* in_sizes, int n_in,
                              void* d_out, int out_size, void* d_ws, size_t ws_size,
                              hipStream_t stream) {
    const float* fea   = (const float*)d_in[0];   // [64,512,128] f32
    const float* coord = (const float*)d_in[1];   // [64,512,2]   f32
    float* out = (float*)d_out;                   // [2,64,512,512] f32

    ASG_fused_kernel<<<dim3(4 * 8 * NB), 256, 0, stream>>>(fea, coord, out);
}

// Round 7
// 56.499 us; speedup vs baseline: 1.3214x; 1.3214x over previous
//
#include <hip/hip_runtime.h>
#include <hip/hip_bf16.h>

typedef short bf16x8 __attribute__((ext_vector_type(8)));
typedef float f32x4  __attribute__((ext_vector_type(4)));

#define NB 64
#define NN 512
#define DD 128

// RNE float -> bf16 (finite inputs)
__device__ __forceinline__ unsigned short f2bf(float f) {
    unsigned int u = __float_as_uint(f);
    unsigned int r = (u + 0x7FFFu + ((u >> 16) & 1u)) >> 16;
    return (unsigned short)r;
}

// Kernel 1: per-row L2 normalize, write bf16 fn into workspace.
// XCD-pinned with the same decode as the adj kernel so batch b's fn rows
// are produced into the L2 of the XCD that will consume them.
__global__ __launch_bounds__(256) void ASG_norm_kernel(
    const float* __restrict__ fea, unsigned int* __restrict__ fn)
{
    const int id   = blockIdx.x;        // 0..2047
    const int xcd  = id & 7;
    const int q    = id >> 3;           // 0..255
    const int b    = xcd + 8 * (q >> 5);
    const int t    = q & 31;            // 32 blocks/batch, 16 rows each
    const int wid  = threadIdx.x >> 6;
    const int lane = threadIdx.x & 63;
    const int row0 = b * NN + t * 16 + wid * 4;
    const float2* src = reinterpret_cast<const float2*>(fea);

    float2 v[4];
    float  s[4];
#pragma unroll
    for (int rr = 0; rr < 4; ++rr) {
        v[rr] = src[(size_t)(row0 + rr) * (DD / 2) + lane];
        s[rr] = v[rr].x * v[rr].x + v[rr].y * v[rr].y;
    }
#pragma unroll
    for (int o = 32; o; o >>= 1) {
#pragma unroll
        for (int rr = 0; rr < 4; ++rr) s[rr] += __shfl_xor(s[rr], o);
    }
#pragma unroll
    for (int rr = 0; rr < 4; ++rr) {
        const float scale = 1.0f / fmaxf(sqrtf(s[rr]), 1e-8f);
        const unsigned short a = f2bf(v[rr].x * scale);
        const unsigned short bb = f2bf(v[rr].y * scale);
        fn[(size_t)(row0 + rr) * (DD / 2) + lane] =
            (unsigned int)a | ((unsigned int)bb << 16);
    }
}

// Kernel 2: per (batch, 128x64 tile). 4 waves, each owns 64x32.
// Double-buffered A-fragment prefetch: loads for m+1 issued before the
// MFMAs/epilogue of m, hiding L2 latency under epilogue VALU + stores.
// Direct NT b32 stores from the MFMA acc layout (no LDS transpose).
__global__ __launch_bounds__(256, 4) void ASG_adj_kernel(
    const unsigned short* __restrict__ fn, const float* __restrict__ coord,
    float* __restrict__ out)
{
    const int id  = blockIdx.x;        // 0..2047
    const int xcd = id & 7;
    const int q   = id >> 3;           // 0..255
    const int b   = xcd + 8 * (q >> 5);
    const int t   = q & 31;
    const int bi  = t >> 3;            // 128-row stripe 0..3
    const int bj  = t & 7;             // 64-col stripe 0..7

    const int tid = threadIdx.x;
    const int wid = tid >> 6, lane = tid & 63;
    const int wr  = wid >> 1, wc = wid & 1;
    const int row0 = bi * 128 + wr * 64;
    const int col0 = bj * 64  + wc * 32;
    const int lo = lane & 15, hi = lane >> 4;

    __shared__ float2 crow[128];
    __shared__ float2 ccol[64];

    const float2* cb = reinterpret_cast<const float2*>(coord) + (size_t)b * NN;
    if (tid < 128)      crow[tid] = cb[bi * 128 + tid];
    else if (tid < 192) ccol[tid - 128] = cb[bj * 64 + (tid - 128)];
    __syncthreads();

    const unsigned short* fb = fn + (size_t)b * NN * DD;
    const int lk = hi * 8;             // k start (bf16 elements)

    // B fragments: col = col0 + n*16 + lo (loop-invariant, 8 dwordx4)
    bf16x8 bfrag[2][4];
#pragma unroll
    for (int n = 0; n < 2; ++n) {
        const unsigned short* p = fb + (size_t)(col0 + n * 16 + lo) * DD + lk;
#pragma unroll
        for (int kk = 0; kk < 4; ++kk)
            bfrag[n][kk] = *reinterpret_cast<const bf16x8*>(p + kk * 32);
    }

    float* outA = out + (size_t)b * NN * NN;
    float* outS = out + (size_t)NB * NN * NN + (size_t)b * NN * NN;

    // per-lane output columns (MFMA C layout: col = lo, row = hi*4 + r)
    const int j0 = col0 + lo;
    const int j1 = col0 + 16 + lo;
    const float2 cj0 = ccol[wc * 32 + lo];
    const float2 cj1 = ccol[wc * 32 + 16 + lo];

#define LOADA(DST, MM)                                                        \
    {                                                                         \
        const unsigned short* p =                                             \
            fb + (size_t)(row0 + (MM) * 16 + lo) * DD + lk;                   \
        _Pragma("unroll")                                                     \
        for (int kk = 0; kk < 4; ++kk)                                        \
            DST[kk] = *reinterpret_cast<const bf16x8*>(p + kk * 32);          \
    }

#define EPI_ELEM(MM, R, CV, CJ, J)                                            \
    {                                                                         \
        const int i = row0 + (MM) * 16 + hi * 4 + (R);                        \
        /* bit-exact match to numpy: mul, mul, add, sqrt (no FMA) */          \
        const float dx = ci.x - (CJ).x;                                       \
        const float dy = ci.y - (CJ).y;                                       \
        const float d2 = __fadd_rn(__fmul_rn(dx, dx), __fmul_rn(dy, dy));     \
        const float dist = __fsqrt_rn(d2);                                    \
        const bool diag = (i == (J));                                         \
        const float av = diag ? 0.0f : (CV) * __expf(-dist);                  \
        const float sv = (!diag && dist < 1.0f) ? 1.0f : 0.0f;                \
        const size_t off = (size_t)i * NN + (J);                              \
        __builtin_nontemporal_store(av, outA + off);                          \
        __builtin_nontemporal_store(sv, outS + off);                          \
    }

#define STEP(MM, CURF, NEXTF, DO_PREF)                                        \
    {                                                                         \
        if (DO_PREF) LOADA(NEXTF, (MM) + 1);                                  \
        f32x4 acc0 = (f32x4){0.f, 0.f, 0.f, 0.f};                             \
        f32x4 acc1 = (f32x4){0.f, 0.f, 0.f, 0.f};                             \
        _Pragma("unroll")                                                     \
        for (int kk = 0; kk < 4; ++kk)                                        \
            acc0 = __builtin_amdgcn_mfma_f32_16x16x32_bf16(                   \
                CURF[kk], bfrag[0][kk], acc0, 0, 0, 0);                       \
        _Pragma("unroll")                                                     \
        for (int kk = 0; kk < 4; ++kk)                                        \
            acc1 = __builtin_amdgcn_mfma_f32_16x16x32_bf16(                   \
                CURF[kk], bfrag[1][kk], acc1, 0, 0, 0);                       \
        _Pragma("unroll")                                                     \
        for (int r = 0; r < 4; ++r) {                                         \
            const float2 ci = crow[wr * 64 + (MM) * 16 + hi * 4 + r];         \
            EPI_ELEM(MM, r, acc0[r], cj0, j0);                                \
            EPI_ELEM(MM, r, acc1[r], cj1, j1);                                \
        }                                                                     \
    }

    bf16x8 af0[4], af1[4];
    LOADA(af0, 0);
    STEP(0, af0, af1, 1);
    STEP(1, af1, af0, 1);
    STEP(2, af0, af1, 1);
    STEP(3, af1, af0, 0);

#undef STEP
#undef EPI_ELEM
#undef LOADA
}

extern "C" void kernel_launch(void* const* d_in, const int* in_sizes, int n_in,
                              void* d_out, int out_size, void* d_ws, size_t ws_size,
                              hipStream_t stream) {
    const float* fea   = (const float*)d_in[0];   // [64,512,128] f32
    const float* coord = (const float*)d_in[1];   // [64,512,2]   f32
    float* out = (float*)d_out;                   // [2,64,512,512] f32
    unsigned int* fn_ws = (unsigned int*)d_ws;    // bf16 fn, 8 MB

    ASG_norm_kernel<<<dim3(2048), 256, 0, stream>>>(fea, fn_ws);
    ASG_adj_kernel<<<dim3(2048), 256, 0, stream>>>(
        (const unsigned short*)fn_ws, coord, out);
}

// Round 8
// 40.808 us; speedup vs baseline: 1.8294x; 1.3845x over previous
//
#include <hip/hip_runtime.h>
#include <hip/hip_bf16.h>

typedef short bf16x8 __attribute__((ext_vector_type(8)));
typedef float f32x4  __attribute__((ext_vector_type(4)));

#define NB 64
#define NN 512
#define DD 128

// RNE float -> bf16 (finite inputs)
__device__ __forceinline__ unsigned short f2bf(float f) {
    unsigned int u = __float_as_uint(f);
    unsigned int r = (u + 0x7FFFu + ((u >> 16) & 1u)) >> 16;
    return (unsigned short)r;
}

// Kernel 1: per-row L2 normalize, write bf16 fn into workspace.
// XCD-pinned with the same decode as the adj kernel so batch b's fn rows
// are produced into the L2 of the XCD that will consume them.
__global__ __launch_bounds__(256) void ASG_norm_kernel(
    const float* __restrict__ fea, unsigned int* __restrict__ fn)
{
    const int id   = blockIdx.x;        // 0..2047
    const int xcd  = id & 7;
    const int q    = id >> 3;           // 0..255
    const int b    = xcd + 8 * (q >> 5);
    const int t    = q & 31;            // 32 blocks/batch, 16 rows each
    const int wid  = threadIdx.x >> 6;
    const int lane = threadIdx.x & 63;
    const int row0 = b * NN + t * 16 + wid * 4;
    const float2* src = reinterpret_cast<const float2*>(fea);

    float2 v[4];
    float  s[4];
#pragma unroll
    for (int rr = 0; rr < 4; ++rr) {
        v[rr] = src[(size_t)(row0 + rr) * (DD / 2) + lane];
        s[rr] = v[rr].x * v[rr].x + v[rr].y * v[rr].y;
    }
#pragma unroll
    for (int o = 32; o; o >>= 1) {
#pragma unroll
        for (int rr = 0; rr < 4; ++rr) s[rr] += __shfl_xor(s[rr], o);
    }
#pragma unroll
    for (int rr = 0; rr < 4; ++rr) {
        const float scale = 1.0f / fmaxf(sqrtf(s[rr]), 1e-8f);
        const unsigned short a = f2bf(v[rr].x * scale);
        const unsigned short bb = f2bf(v[rr].y * scale);
        fn[(size_t)(row0 + rr) * (DD / 2) + lane] =
            (unsigned int)a | ((unsigned int)bb << 16);
    }
}

// Kernel 2: per (batch, 128x64 tile). 4 waves, each owns 64x32.
// R4 structure (LDS transpose + wide x4 stores) + A-frag double-buffer
// prefetch; stores are PLAIN (through L2) — NT removed (R7 post-mortem).
__global__ __launch_bounds__(256, 4) void ASG_adj_kernel(
    const unsigned short* __restrict__ fn, const float* __restrict__ coord,
    float* __restrict__ out)
{
    const int id  = blockIdx.x;        // 0..2047
    const int xcd = id & 7;
    const int q   = id >> 3;           // 0..255
    const int b   = xcd + 8 * (q >> 5);
    const int t   = q & 31;
    const int bi  = t >> 3;            // 128-row stripe 0..3
    const int bj  = t & 7;             // 64-col stripe 0..7

    const int tid = threadIdx.x;
    const int wid = tid >> 6, lane = tid & 63;
    const int wr  = wid >> 1, wc = wid & 1;
    const int row0 = bi * 128 + wr * 64;
    const int col0 = bj * 64  + wc * 32;
    const int lo = lane & 15, hi = lane >> 4;

    __shared__ float2 crow[128];
    __shared__ float2 ccol[64];
    __shared__ float  xpose[4][16 * 36];   // per-wave transpose buf (pad 36)

    const float2* cb = reinterpret_cast<const float2*>(coord) + (size_t)b * NN;
    if (tid < 128)      crow[tid] = cb[bi * 128 + tid];
    else if (tid < 192) ccol[tid - 128] = cb[bj * 64 + (tid - 128)];
    __syncthreads();

    const unsigned short* fb = fn + (size_t)b * NN * DD;
    const int lk = hi * 8;             // k start (bf16 elements)

    // B fragments: col = col0 + n*16 + lo (loop-invariant, 8 dwordx4)
    bf16x8 bfrag[2][4];
#pragma unroll
    for (int n = 0; n < 2; ++n) {
        const unsigned short* p = fb + (size_t)(col0 + n * 16 + lo) * DD + lk;
#pragma unroll
        for (int kk = 0; kk < 4; ++kk)
            bfrag[n][kk] = *reinterpret_cast<const bf16x8*>(p + kk * 32);
    }

    float* outA = out + (size_t)b * NN * NN;
    float* outS = out + (size_t)NB * NN * NN + (size_t)b * NN * NN;
    float* xp = xpose[wid];

    // this lane's 4 output columns (after transpose): jbase..jbase+3
    const int c4 = (lane & 7) * 4;
    const int jbase = col0 + c4;
    float2 cj[4];
#pragma unroll
    for (int q2 = 0; q2 < 4; ++q2) cj[q2] = ccol[wc * 32 + c4 + q2];

#define LOADA(DST, MM)                                                        \
    {                                                                         \
        const unsigned short* p =                                             \
            fb + (size_t)(row0 + (MM) * 16 + lo) * DD + lk;                   \
        _Pragma("unroll")                                                     \
        for (int kk = 0; kk < 4; ++kk)                                        \
            DST[kk] = *reinterpret_cast<const bf16x8*>(p + kk * 32);          \
    }

#define STEP(MM, CURF, NEXTF, DO_PREF)                                        \
    {                                                                         \
        if (DO_PREF) LOADA(NEXTF, (MM) + 1);                                  \
        f32x4 acc[2];                                                         \
        _Pragma("unroll")                                                     \
        for (int n = 0; n < 2; ++n) acc[n] = (f32x4){0.f, 0.f, 0.f, 0.f};     \
        _Pragma("unroll")                                                     \
        for (int n = 0; n < 2; ++n)                                           \
            _Pragma("unroll")                                                 \
            for (int kk = 0; kk < 4; ++kk)                                    \
                acc[n] = __builtin_amdgcn_mfma_f32_16x16x32_bf16(             \
                    CURF[kk], bfrag[n][kk], acc[n], 0, 0, 0);                 \
        /* scatter into LDS: [local_row][local_col], stride 36 */             \
        _Pragma("unroll")                                                     \
        for (int n = 0; n < 2; ++n)                                           \
            _Pragma("unroll")                                                 \
            for (int r = 0; r < 4; ++r)                                       \
                xp[(hi * 4 + r) * 36 + n * 16 + lo] = acc[n][r];              \
        /* read back transposed: 8 rows x 32 cols per pass, x4/lane */        \
        _Pragma("unroll")                                                     \
        for (int p2 = 0; p2 < 2; ++p2) {                                      \
            const int rr = p2 * 8 + (lane >> 3);       /* local row 0..15 */  \
            const f32x4 cv =                                                  \
                *reinterpret_cast<const f32x4*>(&xp[rr * 36 + c4]);           \
            const int i = row0 + (MM) * 16 + rr;                              \
            const float2 ci = crow[wr * 64 + (MM) * 16 + rr];                 \
            f32x4 av, sv;                                                     \
            _Pragma("unroll")                                                 \
            for (int q2 = 0; q2 < 4; ++q2) {                                  \
                const int j = jbase + q2;                                     \
                /* bit-exact numpy chain: mul, mul, add, sqrt (no FMA) */     \
                const float dx = ci.x - cj[q2].x;                             \
                const float dy = ci.y - cj[q2].y;                             \
                const float d2 =                                              \
                    __fadd_rn(__fmul_rn(dx, dx), __fmul_rn(dy, dy));          \
                const float dist = __fsqrt_rn(d2);                            \
                const bool diag = (i == j);                                   \
                av[q2] = diag ? 0.0f : cv[q2] * __expf(-dist);                \
                sv[q2] = (!diag && dist < 1.0f) ? 1.0f : 0.0f;                \
            }                                                                 \
            const size_t off = (size_t)i * NN + jbase;                        \
            *reinterpret_cast<f32x4*>(outA + off) = av;                       \
            *reinterpret_cast<f32x4*>(outS + off) = sv;                       \
        }                                                                     \
    }

    bf16x8 af0[4], af1[4];
    LOADA(af0, 0);
    STEP(0, af0, af1, 1);
    STEP(1, af1, af0, 1);
    STEP(2, af0, af1, 1);
    STEP(3, af1, af0, 0);

#undef STEP
#undef LOADA
}

extern "C" void kernel_launch(void* const* d_in, const int* in_sizes, int n_in,
                              void* d_out, int out_size, void* d_ws, size_t ws_size,
                              hipStream_t stream) {
    const float* fea   = (const float*)d_in[0];   // [64,512,128] f32
    const float* coord = (const float*)d_in[1];   // [64,512,2]   f32
    float* out = (float*)d_out;                   // [2,64,512,512] f32
    unsigned int* fn_ws = (unsigned int*)d_ws;    // bf16 fn, 8 MB

    ASG_norm_kernel<<<dim3(2048), 256, 0, stream>>>(fea, fn_ws);
    ASG_adj_kernel<<<dim3(2048), 256, 0, stream>>>(
        (const unsigned short*)fn_ws, coord, out);
}